// Round 2
// baseline (1040.713 us; speedup 1.0000x reference)
//
#include <hip/hip_runtime.h>
#include <cstdint>
#include <cstddef>

#define BB 4
#define SS 2048
#define HIDD 512
#define HH 8
#define DHH 64
#define DBB 8

typedef __attribute__((ext_vector_type(4))) float f32x4;
typedef __attribute__((ext_vector_type(8))) short s16x8;
typedef __attribute__((ext_vector_type(4))) short s16x4;

__device__ __forceinline__ short f2bf(float x) {
  unsigned u = __builtin_bit_cast(unsigned, x);
  u += 0x7FFFu + ((u >> 16) & 1u);
  return (short)(u >> 16);
}
__device__ __forceinline__ float bf2f(short s) {
  unsigned u = ((unsigned)(unsigned short)s) << 16;
  return __builtin_bit_cast(float, u);
}

// ---------------------------------------------------------------------------
// GEMM: C[m][n] = sum_k X[m][k]*W[n][k] + bias[n].  X: [8192,512] (fp32, or
// bf16 for MODE 3), W: [512,512] fp32.  Tile 128x64, BK=64, 512 threads.
// MODE 0: out bf16 qh [B,H,S,D], *0.125 folded    MODE 1: out bf16 kh [B,H,S,D]
// MODE 2: out bf16 vhT [B,H,D,S]                  MODE 3: out fp32 [8192,512]
// ---------------------------------------------------------------------------
template <int MODE>
__global__ __launch_bounds__(512, 4) void gemm2(const float* __restrict__ Xf,
                                                const short* __restrict__ Xb,
                                                const float* __restrict__ W,
                                                const float* __restrict__ bias,
                                                float* __restrict__ outF,
                                                short* __restrict__ outB) {
  __shared__ short As[128][72];  // pad 72: frag b128 reads 2-way (free)
  __shared__ short Bs[64][72];
  const int tid = threadIdx.x;
  const int wave = tid >> 6, lane = tid & 63;
  const int quad = lane >> 4, m16 = lane & 15;
  const int m0 = blockIdx.y * 128, n0 = blockIdx.x * 64;
  const int wm = (wave & 1) * 64, wn = (wave >> 1) * 16;

  f32x4 acc[4];
#pragma unroll
  for (int a = 0; a < 4; a++) acc[a] = (f32x4){0.f, 0.f, 0.f, 0.f};

  const int xrow = tid >> 2, xcb = (tid & 3) * 16;  // X: 4 thr/row, 16 elems each
  const int wrow = tid >> 3, wcb = (tid & 7) * 8;   // W: 8 thr/row, 8 elems each

  for (int k0 = 0; k0 < HIDD; k0 += 64) {
    // ---- stage X tile (convert fp32->bf16 unless MODE 3) ----
    if (MODE == 3) {
      s16x8 x0 = *(const s16x8*)(Xb + (size_t)(m0 + xrow) * HIDD + k0 + xcb);
      s16x8 x1 = *(const s16x8*)(Xb + (size_t)(m0 + xrow) * HIDD + k0 + xcb + 8);
      *(s16x8*)(&As[xrow][xcb]) = x0;
      *(s16x8*)(&As[xrow][xcb + 8]) = x1;
    } else {
      const float* xp = Xf + (size_t)(m0 + xrow) * HIDD + k0 + xcb;
      f32x4 xv[4];
#pragma unroll
      for (int i = 0; i < 4; i++) xv[i] = *(const f32x4*)(xp + i * 4);
      s16x8 pk0, pk1;
#pragma unroll
      for (int j = 0; j < 4; j++) { pk0[j] = f2bf(xv[0][j]); pk0[4 + j] = f2bf(xv[1][j]); }
#pragma unroll
      for (int j = 0; j < 4; j++) { pk1[j] = f2bf(xv[2][j]); pk1[4 + j] = f2bf(xv[3][j]); }
      *(s16x8*)(&As[xrow][xcb]) = pk0;
      *(s16x8*)(&As[xrow][xcb + 8]) = pk1;
    }
    // ---- stage W tile ----
    {
      const float* wp = W + (size_t)(n0 + wrow) * HIDD + k0 + wcb;
      f32x4 w0 = *(const f32x4*)(wp);
      f32x4 w1 = *(const f32x4*)(wp + 4);
      s16x8 pk;
#pragma unroll
      for (int j = 0; j < 4; j++) { pk[j] = f2bf(w0[j]); pk[4 + j] = f2bf(w1[j]); }
      *(s16x8*)(&Bs[wrow][wcb]) = pk;
    }
    __syncthreads();
#pragma unroll
    for (int kc = 0; kc < 2; kc++) {
      s16x8 bf = *(const s16x8*)(&Bs[wn + m16][kc * 32 + quad * 8]);
#pragma unroll
      for (int a = 0; a < 4; a++) {
        s16x8 af = *(const s16x8*)(&As[wm + a * 16 + m16][kc * 32 + quad * 8]);
        acc[a] = __builtin_amdgcn_mfma_f32_16x16x32_bf16(af, bf, acc[a], 0, 0, 0);
      }
    }
    __syncthreads();
  }

  const int n = n0 + wn + m16;
  const float bn = bias[n];
#pragma unroll
  for (int a = 0; a < 4; a++) {
    const int mb = m0 + wm + a * 16 + quad * 4;  // rows mb..mb+3 (r = reg)
    if (MODE == 2) {
      int b_ = mb >> 11, s = mb & 2047, h = n >> 6, d = n & 63;
      s16x4 pk;
#pragma unroll
      for (int r = 0; r < 4; r++) pk[r] = f2bf(acc[a][r] + bn);
      *(s16x4*)(outB + ((size_t)(b_ * HH + h) * DHH + d) * SS + s) = pk;
    } else {
#pragma unroll
      for (int r = 0; r < 4; r++) {
        int m = mb + r;
        float val = acc[a][r] + bn;
        if (MODE == 0) {
          int b_ = m >> 11, s = m & 2047, h = n >> 6, d = n & 63;
          outB[((size_t)(b_ * HH + h) * SS + s) * DHH + d] = f2bf(val * 0.125f);
        } else if (MODE == 1) {
          int b_ = m >> 11, s = m & 2047, h = n >> 6, d = n & 63;
          outB[((size_t)(b_ * HH + h) * SS + s) * DHH + d] = f2bf(val);
        } else {
          outF[(size_t)m * HIDD + n] = val;
        }
      }
    }
  }
}

// ---------------------------------------------------------------------------
// Flash attention, bias fused.  Block = (b, 16 q rows, all 8 heads); wave = head.
// K-tile 64, 32 iterations, ONE barrier per iteration (double-buffered bias LDS).
// K/V fragments loaded directly from global (L2-resident; XCD swizzle groups
// each batch's blocks onto 2 XCDs so K+V (4 MB) fits the per-XCD L2).
// attn_bias (537 MB) read exactly once, nontemporal, prefetched one tile ahead.
// ---------------------------------------------------------------------------
__global__ __launch_bounds__(512, 4) void flash_attn(const short* __restrict__ qh,
                                                     const short* __restrict__ kh,
                                                     const short* __restrict__ vh,
                                                     const float* __restrict__ attn_bias,
                                                     const float* __restrict__ Wb,
                                                     const float* __restrict__ bb,
                                                     short* __restrict__ attn_out) {
  __shared__ short bp[2][HH][16][68];  // projected bias bf16, double-buffered
  __shared__ short pbuf[HH][16][76];   // per-wave P tile (C-layout -> A-layout bounce)
  __shared__ float wbs[72];            // Wb[8][8] + bb[8]

  const int tid = threadIdx.x;
  const int wave = tid >> 6, lane = tid & 63;
  const int quad = lane >> 4, m16 = lane & 15;
  const int h = wave;
  // XCD swizzle: batch b -> XCDs {2b, 2b+1}
  const int j = blockIdx.x;
  const int b = (j & 7) >> 1;
  const int w = ((j >> 3) << 1) | (j & 1);
  const int q0 = w << 4;

  if (tid < 72) wbs[tid] = (tid < 64) ? Wb[tid] : bb[tid - 64];

  // Q A-fragments (already *0.125 from projection)
  const size_t qoff = ((size_t)((b * HH + h) * SS) + q0 + m16) * DHH;
  const s16x8 qf0 = *(const s16x8*)(qh + qoff + quad * 8);
  const s16x8 qf1 = *(const s16x8*)(qh + qoff + 32 + quad * 8);

  f32x4 oacc[4];
#pragma unroll
  for (int dt = 0; dt < 4; dt++) oacc[dt] = (f32x4){0.f, 0.f, 0.f, 0.f};
  float m_r[4], l_r[4];
#pragma unroll
  for (int r = 0; r < 4; r++) { m_r[r] = -3.0e38f; l_r[r] = 0.f; }

  // this thread's two bias positions: q row ql, key cols kc2, kc2+1
  const int ql = tid >> 5, kc2 = (tid & 31) * 2;
  const float* bbase = attn_bias + ((size_t)(b * SS + q0 + ql) * SS + kc2) * DBB;

  f32x4 pre[4];
#pragma unroll
  for (int i = 0; i < 4; i++)
    pre[i] = __builtin_nontemporal_load((const f32x4*)(bbase) + i);

  const size_t khb = (size_t)((b * HH + h) * SS) * DHH;   // kh[b,h] base
  const size_t vhb = (size_t)((b * HH + h) * DHH) * SS;   // vhT[b,h] base

  __syncthreads();  // wbs ready

  for (int it = 0; it < 32; ++it) {
    const int buf = it & 1;
    const int k0 = it * 64;

    // ---- project prefetched raw bias -> bp[buf] (2 positions x 8 heads) ----
#pragma unroll
    for (int h2 = 0; h2 < HH; h2++) {
      float a0 = wbs[64 + h2], a1 = a0;
#pragma unroll
      for (int d = 0; d < 4; d++) {
        a0 += pre[0][d] * wbs[h2 * 8 + d];
        a0 += pre[1][d] * wbs[h2 * 8 + 4 + d];
        a1 += pre[2][d] * wbs[h2 * 8 + d];
        a1 += pre[3][d] * wbs[h2 * 8 + 4 + d];
      }
      unsigned pk = (unsigned)(unsigned short)f2bf(a0) |
                    ((unsigned)(unsigned short)f2bf(a1) << 16);
      *(unsigned*)(&bp[buf][h2][ql][kc2]) = pk;
    }
    __syncthreads();  // bp[buf] ready (also: all reads of bp[buf] from it-2 done)

    // ---- issue next tile's bias prefetch (in flight through softmax+PV) ----
    {
      const int kn = (it < 31) ? (it + 1) * 64 : it * 64;
      const float* nb = bbase + (size_t)kn * DBB;
#pragma unroll
      for (int i = 0; i < 4; i++)
        pre[i] = __builtin_nontemporal_load((const f32x4*)(nb) + i);
    }

    // ---- QK^T: 16q x 64k for this wave's head, K frags direct from global ----
    f32x4 sc[4];
#pragma unroll
    for (int nt = 0; nt < 4; nt++) {
      const short* kp = kh + khb + (size_t)(k0 + nt * 16 + m16) * DHH;
      s16x8 kf0 = *(const s16x8*)(kp + quad * 8);
      s16x8 kf1 = *(const s16x8*)(kp + 32 + quad * 8);
      f32x4 z = (f32x4){0.f, 0.f, 0.f, 0.f};
      z = __builtin_amdgcn_mfma_f32_16x16x32_bf16(qf0, kf0, z, 0, 0, 0);
      z = __builtin_amdgcn_mfma_f32_16x16x32_bf16(qf1, kf1, z, 0, 0, 0);
      sc[nt] = z;
    }

    // ---- online softmax (C layout: row = quad*4+r, col = nt*16 + m16) ----
#pragma unroll
    for (int r = 0; r < 4; r++) {
      const int row = quad * 4 + r;
      float s0 = sc[0][r] + bf2f(bp[buf][h][row][m16]);
      float s1 = sc[1][r] + bf2f(bp[buf][h][row][16 + m16]);
      float s2 = sc[2][r] + bf2f(bp[buf][h][row][32 + m16]);
      float s3 = sc[3][r] + bf2f(bp[buf][h][row][48 + m16]);
      float v = fmaxf(fmaxf(s0, s1), fmaxf(s2, s3));
      v = fmaxf(v, __shfl_xor(v, 1, 16));
      v = fmaxf(v, __shfl_xor(v, 2, 16));
      v = fmaxf(v, __shfl_xor(v, 4, 16));
      v = fmaxf(v, __shfl_xor(v, 8, 16));
      const float nm = fmaxf(m_r[r], v);
      const float al = __expf(m_r[r] - nm);
      m_r[r] = nm;
      float p0 = __expf(s0 - nm), p1 = __expf(s1 - nm);
      float p2 = __expf(s2 - nm), p3 = __expf(s3 - nm);
      float rs = (p0 + p1) + (p2 + p3);
      rs += __shfl_xor(rs, 1, 16);
      rs += __shfl_xor(rs, 2, 16);
      rs += __shfl_xor(rs, 4, 16);
      rs += __shfl_xor(rs, 8, 16);
      l_r[r] = l_r[r] * al + rs;
#pragma unroll
      for (int dt = 0; dt < 4; dt++) oacc[dt][r] *= al;
      pbuf[h][row][m16] = f2bf(p0);
      pbuf[h][row][16 + m16] = f2bf(p1);
      pbuf[h][row][32 + m16] = f2bf(p2);
      pbuf[h][row][48 + m16] = f2bf(p3);
    }

    // ---- PV: O += P(16x64) @ V^T, V frags direct from global ----
    const s16x8 pf0 = *(const s16x8*)(&pbuf[h][m16][quad * 8]);
    const s16x8 pf1 = *(const s16x8*)(&pbuf[h][m16][32 + quad * 8]);
#pragma unroll
    for (int dt = 0; dt < 4; dt++) {
      const short* vp = vh + vhb + (size_t)(dt * 16 + m16) * SS + k0;
      s16x8 vf0 = *(const s16x8*)(vp + quad * 8);
      s16x8 vf1 = *(const s16x8*)(vp + 32 + quad * 8);
      oacc[dt] = __builtin_amdgcn_mfma_f32_16x16x32_bf16(pf0, vf0, oacc[dt], 0, 0, 0);
      oacc[dt] = __builtin_amdgcn_mfma_f32_16x16x32_bf16(pf1, vf1, oacc[dt], 0, 0, 0);
    }
    // no second barrier: bp double-buffered, pbuf wave-local
  }

  // epilogue: attn_out[b, s, h*64+d] bf16
#pragma unroll
  for (int dt = 0; dt < 4; dt++)
#pragma unroll
    for (int r = 0; r < 4; r++) {
      float val = oacc[dt][r] / l_r[r];
      attn_out[(size_t)(b * SS + q0 + quad * 4 + r) * HIDD + h * DHH + dt * 16 + m16] = f2bf(val);
    }
}

extern "C" void kernel_launch(void* const* d_in, const int* in_sizes, int n_in,
                              void* d_out, int out_size, void* d_ws, size_t ws_size,
                              hipStream_t stream) {
  const float* q = (const float*)d_in[0];
  const float* k = (const float*)d_in[1];
  const float* v = (const float*)d_in[2];
  const float* attn_bias = (const float*)d_in[3];
  const float* Wq = (const float*)d_in[4];
  const float* bq = (const float*)d_in[5];
  const float* Wk = (const float*)d_in[6];
  const float* bk = (const float*)d_in[7];
  const float* Wv = (const float*)d_in[8];
  const float* bv = (const float*)d_in[9];
  const float* Wb = (const float*)d_in[10];
  const float* bb = (const float*)d_in[11];
  const float* Wo = (const float*)d_in[12];
  const float* bo = (const float*)d_in[13];
  float* out = (float*)d_out;

  // workspace: qh/kh/vhT/attn bf16, 8.39 MB each = 33.6 MB total
  short* qh = (short*)d_ws;
  short* kh = qh + (size_t)4194304;
  short* vhT = kh + (size_t)4194304;
  short* attn_b = vhT + (size_t)4194304;

  dim3 g(8, 64), blk(512);
  gemm2<0><<<g, blk, 0, stream>>>(q, nullptr, Wq, bq, nullptr, qh);
  gemm2<1><<<g, blk, 0, stream>>>(k, nullptr, Wk, bk, nullptr, kh);
  gemm2<2><<<g, blk, 0, stream>>>(v, nullptr, Wv, bv, nullptr, vhT);
  flash_attn<<<512, blk, 0, stream>>>(qh, kh, vhT, attn_bias, Wb, bb, attn_b);
  gemm2<3><<<g, blk, 0, stream>>>(nullptr, attn_b, Wo, bo, out, nullptr);
}